// Round 1
// baseline (834.754 us; speedup 1.0000x reference)
//
#include <hip/hip_runtime.h>

// UltraSparseMoE: B=2,S=1024,D=1024,H=4096,E=8,K=2,NS=1. All fp32 in/out.
// Strategy: fp16-MFMA GEMMs. Pre-transpose+convert weights fp32->fp16 into ws
// (makes B-operand K-consecutive), then m97-style 128x128-tile GEMMs.
// GEMM1 fuses silu(x@W1)*(x@W2) -> h (fp16, ws). GEMM2 (split-K=2) does
// h@W3 * weight -> atomicAdd into zeroed out. Router exact fp32.

#define TD 2048
#define DD 1024
#define HH 4096
#define NEXP 8
#define LDAH 40  // LDS row stride in halfs (32 + 8 pad -> 80B rows, conflict-free b128)

typedef _Float16 f16x8 __attribute__((ext_vector_type(8)));
typedef _Float16 f16x4 __attribute__((ext_vector_type(4)));
typedef float f32x4 __attribute__((ext_vector_type(4)));

// ---- workspace layout (bytes) ----
#define WS_COUNTS   0
#define WS_CURS     64
#define WS_HBASE    128
#define WS_TOKLIST  256                     // int[8*2048] = 65536
#define WS_TOKW     65792                   // float[8*2048]
#define WS_TOPI     131328                  // int[4096]
#define WS_TOPW     147712                  // float[4096]
#define WS_H        262144                  // fp16 h [7168][4096] = 58,720,256 B
#define WS_WT       (262144 + 58720256)     // fp16 transposed weights, 18 mats * 8MB
// total needed ~= 210 MB

// ---------------- router ----------------
__global__ __launch_bounds__(256) void k_router(const float* __restrict__ x,
    const float* __restrict__ rw, float* __restrict__ logits,
    int* __restrict__ topi, float* __restrict__ topw, int* __restrict__ counts) {
  int wv = threadIdx.x >> 6, lane = threadIdx.x & 63;
  int t = blockIdx.x * 4 + wv;
  const float* xt = x + (size_t)t * DD;
  float lg[NEXP];
#pragma unroll
  for (int e = 0; e < NEXP; ++e) {
    const float* we = rw + e * DD;
    float acc = 0.f;
#pragma unroll
    for (int j = 0; j < DD / 64; ++j) acc += xt[j * 64 + lane] * we[j * 64 + lane];
#pragma unroll
    for (int off = 32; off; off >>= 1) acc += __shfl_xor(acc, off);
    lg[e] = acc;
  }
  if (lane == 0) {
    float m = lg[0];
#pragma unroll
    for (int e = 1; e < NEXP; ++e) m = fmaxf(m, lg[e]);
    float p[NEXP];
#pragma unroll
    for (int e = 0; e < NEXP; ++e) p[e] = __expf(lg[e] - m);
    int i0 = 0; float p0 = p[0];
#pragma unroll
    for (int e = 1; e < NEXP; ++e) if (p[e] > p0) { p0 = p[e]; i0 = e; }
    int i1 = -1; float p1 = -1.f;
#pragma unroll
    for (int e = 0; e < NEXP; ++e) if (e != i0 && p[e] > p1) { p1 = p[e]; i1 = e; }
    float wsum = p0 + p1;
#pragma unroll
    for (int e = 0; e < NEXP; ++e) logits[t * NEXP + e] = lg[e];
    topi[t * 2] = i0; topi[t * 2 + 1] = i1;
    topw[t * 2] = p0 / wsum; topw[t * 2 + 1] = p1 / wsum;
    atomicAdd(&counts[i0], 1); atomicAdd(&counts[i1], 1);
  }
}

__global__ void k_offsets(const int* __restrict__ counts, int* __restrict__ hbase) {
  if (threadIdx.x == 0) {
    int base = TD;  // shared-expert rows occupy h[0..2047]
    for (int e = 0; e < NEXP; ++e) { hbase[e] = base; base += (counts[e] + 127) & ~127; }
  }
}

__global__ void k_scatter(const int* __restrict__ topi, const float* __restrict__ topw,
                          int* __restrict__ curs, int* __restrict__ tokl, float* __restrict__ tokw) {
  int tid = blockIdx.x * 256 + threadIdx.x;
  if (tid >= TD * 2) return;
  int e = topi[tid];
  int pos = atomicAdd(&curs[e], 1);
  tokl[e * TD + pos] = tid >> 1;
  tokw[e * TD + pos] = topw[tid];
}

// ---------------- transpose + fp32->fp16 ----------------
__device__ __forceinline__ void transpose_tile(const float* __restrict__ src,
    _Float16* __restrict__ dst, int R, int C, int r0, int c0) {
  __shared__ _Float16 tile[64][68];
  int t = threadIdx.x;
#pragma unroll
  for (int i = 0; i < 4; ++i) {
    int r = (t >> 4) + i * 16;
    int c = (t & 15) * 4;
    float4 v = *(const float4*)(src + (size_t)(r0 + r) * C + c0 + c);
    *(f16x4*)&tile[r][c] = (f16x4){(_Float16)v.x, (_Float16)v.y, (_Float16)v.z, (_Float16)v.w};
  }
  __syncthreads();
#pragma unroll
  for (int i = 0; i < 2; ++i) {
    int cc = (t >> 3) + i * 32;
    int rr = (t & 7) * 8;
    f16x8 hv;
#pragma unroll
    for (int j = 0; j < 8; ++j) hv[j] = tile[rr + j][cc];
    *(f16x8*)(dst + (size_t)(c0 + cc) * R + r0 + rr) = hv;
  }
}

// phase 1: [1024][4096] mats: slot 0=sw1, 1=sw2, 2..9=w1[e], 10..17=w2[e]
__global__ __launch_bounds__(256) void k_tr1(const float* __restrict__ sw1, const float* __restrict__ sw2,
    const float* __restrict__ w1, const float* __restrict__ w2, _Float16* __restrict__ wt) {
  int id = blockIdx.y;
  const float* src = (id == 0) ? sw1 : (id == 1) ? sw2
                   : (id < 10) ? w1 + (size_t)(id - 2) * DD * HH
                               : w2 + (size_t)(id - 10) * DD * HH;
  _Float16* dst = wt + (size_t)id * DD * HH;
  transpose_tile(src, dst, DD, HH, (blockIdx.x >> 6) * 64, (blockIdx.x & 63) * 64);
}

// phase 2 (after gemm1, reuses wt region): [4096][1024] mats: 0=sw3, 1..8=w3[e]
__global__ __launch_bounds__(256) void k_tr2(const float* __restrict__ sw3,
    const float* __restrict__ w3, _Float16* __restrict__ wt) {
  int id = blockIdx.y;
  const float* src = (id == 0) ? sw3 : w3 + (size_t)(id - 1) * HH * DD;
  _Float16* dst = wt + (size_t)id * HH * DD;
  transpose_tile(src, dst, HH, DD, (blockIdx.x >> 4) * 64, (blockIdx.x & 15) * 64);
}

// ---------------- GEMM1: h = silu(x@W1) * (x@W2), fp16 out ----------------
__global__ __launch_bounds__(256, 2) void k_gemm1(
    const float* __restrict__ x, const _Float16* __restrict__ wt,
    const int* __restrict__ counts, const int* __restrict__ hbase,
    const int* __restrict__ tok_list, _Float16* __restrict__ h) {
  __shared__ _Float16 lA[128 * LDAH];
  __shared__ _Float16 lB1[128 * LDAH];
  __shared__ _Float16 lB2[128 * LDAH];
  __shared__ int stok[128];

  int slot = blockIdx.y;
  const _Float16 *w1t, *w2t;
  int hrow0;
  if (slot < 16) {
    w1t = wt;
    w2t = wt + (size_t)1 * DD * HH;
    hrow0 = slot * 128;
  } else {
    int e = (slot - 16) >> 4, rt = (slot - 16) & 15;
    if (rt * 128 >= counts[e]) return;
    w1t = wt + (size_t)(2 + e) * DD * HH;
    w2t = wt + (size_t)(10 + e) * DD * HH;
    hrow0 = hbase[e] + rt * 128;
  }
  if (threadIdx.x < 128) {
    int tok;
    if (slot < 16) tok = hrow0 + threadIdx.x;
    else {
      int e = (slot - 16) >> 4, rt = (slot - 16) & 15;
      tok = tok_list[e * TD + rt * 128 + threadIdx.x];  // pads are 0 (memset) -> safe reads
    }
    stok[threadIdx.x] = tok;
  }

  int n0 = blockIdx.x * 128;
  int wv = threadIdx.x >> 6, lane = threadIdx.x & 63;
  int wm = (wv & 1) * 64, wn = (wv >> 1) * 64;
  f32x4 acc1[4][4] = {}; f32x4 acc2[4][4] = {};

  for (int kk = 0; kk < DD; kk += 32) {
    __syncthreads();
    { // stage A: x fp32 -> fp16 LDS [128][40]
      int r = threadIdx.x >> 3;
      int c = (threadIdx.x & 7) * 4;
#pragma unroll
      for (int i = 0; i < 4; ++i) {
        int row = r + i * 32;
        float4 v = *(const float4*)(x + (size_t)stok[row] * DD + kk + c);
        *(f16x4*)&lA[row * LDAH + c] = (f16x4){(_Float16)v.x, (_Float16)v.y, (_Float16)v.z, (_Float16)v.w};
      }
    }
    { // stage B1/B2: pre-transposed fp16, b128 both sides
      int rr = lane >> 2;
      int seg = (lane & 3) * 8;
#pragma unroll
      for (int j = 0; j < 4; ++j) {
        int task = wv + j * 4;      // 16 tasks: 2 mats x 8 sub-tiles
        int mat = task >> 3, it = task & 7;
        int row = it * 16 + rr;
        const _Float16* src = (mat ? w2t : w1t) + (size_t)(n0 + row) * DD + kk + seg;
        _Float16* dst = (mat ? lB2 : lB1) + row * LDAH + seg;
        *(f16x8*)dst = *(const f16x8*)src;
      }
    }
    __syncthreads();
    f16x8 af[4];
    int rA = lane & 15, g = (lane >> 4) * 8;
#pragma unroll
    for (int mi = 0; mi < 4; ++mi)
      af[mi] = *(const f16x8*)&lA[(wm + mi * 16 + rA) * LDAH + g];
#pragma unroll
    for (int ni = 0; ni < 4; ++ni) {
      f16x8 b1 = *(const f16x8*)&lB1[(wn + ni * 16 + rA) * LDAH + g];
      f16x8 b2 = *(const f16x8*)&lB2[(wn + ni * 16 + rA) * LDAH + g];
#pragma unroll
      for (int mi = 0; mi < 4; ++mi) {
        acc1[mi][ni] = __builtin_amdgcn_mfma_f32_16x16x32_f16(af[mi], b1, acc1[mi][ni], 0, 0, 0);
        acc2[mi][ni] = __builtin_amdgcn_mfma_f32_16x16x32_f16(af[mi], b2, acc2[mi][ni], 0, 0, 0);
      }
    }
  }
  // epilogue: h = silu(a)*b, fp16
#pragma unroll
  for (int mi = 0; mi < 4; ++mi) {
#pragma unroll
    for (int ni = 0; ni < 4; ++ni) {
#pragma unroll
      for (int i = 0; i < 4; ++i) {
        int r = wm + mi * 16 + (lane >> 4) * 4 + i;
        int c = wn + ni * 16 + (lane & 15);
        float a = acc1[mi][ni][i], b = acc2[mi][ni][i];
        float hv = (a / (1.f + __expf(-a))) * b;
        h[(size_t)(hrow0 + r) * HH + n0 + c] = (_Float16)hv;
      }
    }
  }
}

// ---------------- GEMM2: out += w * (h @ W3), split-K=2, atomic ----------------
__global__ __launch_bounds__(256, 2) void k_gemm2(
    const _Float16* __restrict__ h, const _Float16* __restrict__ wt,
    const int* __restrict__ counts, const int* __restrict__ hbase,
    const int* __restrict__ tok_list, const float* __restrict__ tok_w,
    float* __restrict__ out) {
  __shared__ _Float16 lA[128 * LDAH];
  __shared__ _Float16 lB[128 * LDAH];
  __shared__ int stok[128];
  __shared__ float swt[128];

  int slot = blockIdx.y;
  const _Float16* w3t;
  int hrow0, cnt;
  if (slot < 16) {
    w3t = wt;
    hrow0 = slot * 128; cnt = 128;
  } else {
    int e = (slot - 16) >> 4, rt = (slot - 16) & 15;
    cnt = counts[e] - rt * 128;
    if (cnt <= 0) return;
    if (cnt > 128) cnt = 128;
    w3t = wt + (size_t)(1 + e) * HH * DD;
    hrow0 = hbase[e] + rt * 128;
  }
  if (threadIdx.x < 128) {
    int tok; float w;
    if (slot < 16) { tok = hrow0 + threadIdx.x; w = 1.f; }
    else {
      int e = (slot - 16) >> 4, rt = (slot - 16) & 15;
      int idx = rt * 128 + threadIdx.x;
      tok = tok_list[e * TD + idx]; w = tok_w[e * TD + idx];
    }
    stok[threadIdx.x] = tok; swt[threadIdx.x] = w;
  }

  int n0 = blockIdx.x * 128;
  int kz0 = blockIdx.z * (HH / 2);
  int wv = threadIdx.x >> 6, lane = threadIdx.x & 63;
  int wm = (wv & 1) * 64, wn = (wv >> 1) * 64;
  f32x4 acc[4][4] = {};

  for (int kk = kz0; kk < kz0 + HH / 2; kk += 32) {
    __syncthreads();
    {
      int rr = lane >> 2;
      int seg = (lane & 3) * 8;
#pragma unroll
      for (int j = 0; j < 4; ++j) {
        int task = wv + j * 4;      // 16 tasks: A(8) + B(8)
        int mat = task >> 3, it = task & 7;
        int row = it * 16 + rr;
        const _Float16* src = mat ? (w3t + (size_t)(n0 + row) * HH + kk + seg)
                                  : (h + (size_t)(hrow0 + row) * HH + kk + seg);
        _Float16* dst = (mat ? lB : lA) + row * LDAH + seg;
        *(f16x8*)dst = *(const f16x8*)src;
      }
    }
    __syncthreads();
    f16x8 af[4];
    int rA = lane & 15, g = (lane >> 4) * 8;
#pragma unroll
    for (int mi = 0; mi < 4; ++mi)
      af[mi] = *(const f16x8*)&lA[(wm + mi * 16 + rA) * LDAH + g];
#pragma unroll
    for (int ni = 0; ni < 4; ++ni) {
      f16x8 bf = *(const f16x8*)&lB[(wn + ni * 16 + rA) * LDAH + g];
#pragma unroll
      for (int mi = 0; mi < 4; ++mi)
        acc[mi][ni] = __builtin_amdgcn_mfma_f32_16x16x32_f16(af[mi], bf, acc[mi][ni], 0, 0, 0);
    }
  }
#pragma unroll
  for (int mi = 0; mi < 4; ++mi) {
#pragma unroll
    for (int i = 0; i < 4; ++i) {
      int r = wm + mi * 16 + (lane >> 4) * 4 + i;
      if (r < cnt) {
        int tok = stok[r]; float w = swt[r];
#pragma unroll
        for (int ni = 0; ni < 4; ++ni) {
          int c = wn + ni * 16 + (lane & 15);
          atomicAdd(&out[(size_t)tok * DD + n0 + c], w * acc[mi][ni][i]);
        }
      }
    }
  }
}

// ---------------- launcher ----------------
extern "C" void kernel_launch(void* const* d_in, const int* in_sizes, int n_in,
                              void* d_out, int out_size, void* d_ws, size_t ws_size,
                              hipStream_t stream) {
  const float* x   = (const float*)d_in[0];
  const float* sw1 = (const float*)d_in[1];
  const float* sw2 = (const float*)d_in[2];
  const float* sw3 = (const float*)d_in[3];
  const float* w1  = (const float*)d_in[4];
  const float* w2  = (const float*)d_in[5];
  const float* w3  = (const float*)d_in[6];
  const float* rw  = (const float*)d_in[7];
  float* out = (float*)d_out;
  char* ws = (char*)d_ws;

  int*   counts = (int*)(ws + WS_COUNTS);
  int*   curs   = (int*)(ws + WS_CURS);
  int*   hbase  = (int*)(ws + WS_HBASE);
  int*   tokl   = (int*)(ws + WS_TOKLIST);
  float* tokw   = (float*)(ws + WS_TOKW);
  int*   topi   = (int*)(ws + WS_TOPI);
  float* topw   = (float*)(ws + WS_TOPW);
  _Float16* hbuf = (_Float16*)(ws + WS_H);
  _Float16* wt   = (_Float16*)(ws + WS_WT);

  // zero routing metadata + token lists; zero the out tensor (gemm2 accumulates)
  hipMemsetAsync(ws, 0, WS_TOKLIST + 65536, stream);
  hipMemsetAsync(out, 0, (size_t)TD * DD * sizeof(float), stream);

  k_router<<<TD / 4, 256, 0, stream>>>(x, rw, out + (size_t)TD * DD, topi, topw, counts);
  k_offsets<<<1, 64, 0, stream>>>(counts, hbase);
  k_scatter<<<16, 256, 0, stream>>>(topi, topw, curs, tokl, tokw);

  k_tr1<<<dim3(1024, 18), 256, 0, stream>>>(sw1, sw2, w1, w2, wt);
  k_gemm1<<<dim3(HH / 128, 144), 256, 0, stream>>>(x, wt, counts, hbase, tokl, hbuf);
  k_tr2<<<dim3(1024, 9), 256, 0, stream>>>(sw3, w3, wt);  // reuses wt region after gemm1
  k_gemm2<<<dim3(DD / 128, 144, 2), 256, 0, stream>>>(hbuf, wt, counts, hbase, tokl, tokw, out);
}

// Round 2
// 794.707 us; speedup vs baseline: 1.0504x; 1.0504x over previous
//
#include <hip/hip_runtime.h>

// UltraSparseMoE: B=2,S=1024,D=1024,H=4096,E=8,K=2,NS=1. fp32 in/out.
// R2: m97-style GEMMs (global_load_lds width=16, XOR-swizzled LDS tiles,
// 2-way-max bank aliasing), atomic-free gemm2 (split-K partial fp16 buffers
// + gather-combine epilogue kernel).

#define TD 2048
#define DD 1024
#define HH 4096
#define NEXP 8

typedef _Float16 f16x8 __attribute__((ext_vector_type(8)));
typedef _Float16 f16x4 __attribute__((ext_vector_type(4)));
typedef float f32x4 __attribute__((ext_vector_type(4)));

// ---- workspace layout (bytes) ----
#define WS_COUNTS   0
#define WS_CURS     64
#define WS_HBASE    128
#define WS_TOKLIST  256                       // int[8*2048] -> ends 65792
#define WS_TOPI     65792                     // int[4096]
#define WS_TOPW     82176                     // float[4096]
#define WS_POS      98560                     // int[4096]
#define WS_XH       131072                    // fp16 x [2048][1024] = 4 MB
#define WS_H        4325376                   // fp16 h [7168][4096] = 58.7 MB
#define WS_WT       63045632                  // fp16 transposed weights, 18 slots x 8 MB
#define WTSLOT      ((size_t)DD * HH)         // 4M halfs = 8 MB
// y0/y1 (fp16 [7168][1024] = 14.7 MB each) live in dead wt slots 9-12 during gemm2.

// ---- async global->LDS, width 16 ----
typedef __attribute__((address_space(3))) void lds_void;
typedef const __attribute__((address_space(1))) void gbl_void;
__device__ __forceinline__ void gld16(void* l, const void* g) {
  __builtin_amdgcn_global_load_lds((gbl_void*)g, (lds_void*)l, 16, 0, 0);
}

// swizzled fragment read: tile is [128 rows][32 halfs], granule q stored at q^((row>>1)&3)
__device__ __forceinline__ f16x8 frag_ld(const _Float16* tile, int r, int qsel) {
  int q = qsel ^ ((r >> 1) & 3);
  return *(const f16x8*)((const char*)tile + r * 64 + q * 16);
}

// ---------------- x -> fp16 ----------------
__global__ __launch_bounds__(256) void k_xh(const float* __restrict__ x, _Float16* __restrict__ xh) {
  int i = (blockIdx.x * 256 + threadIdx.x) * 8;
  float4 a = *(const float4*)(x + i), b = *(const float4*)(x + i + 4);
  f16x8 v = {(_Float16)a.x, (_Float16)a.y, (_Float16)a.z, (_Float16)a.w,
             (_Float16)b.x, (_Float16)b.y, (_Float16)b.z, (_Float16)b.w};
  *(f16x8*)(xh + i) = v;
}

// ---------------- router ----------------
__global__ __launch_bounds__(256) void k_router(const float* __restrict__ x,
    const float* __restrict__ rw, float* __restrict__ logits,
    int* __restrict__ topi, float* __restrict__ topw, int* __restrict__ counts) {
  int wv = threadIdx.x >> 6, lane = threadIdx.x & 63;
  int t = blockIdx.x * 4 + wv;
  const float* xt = x + (size_t)t * DD;
  float lg[NEXP];
#pragma unroll
  for (int e = 0; e < NEXP; ++e) {
    const float* we = rw + e * DD;
    float acc = 0.f;
#pragma unroll
    for (int j = 0; j < DD / 64; ++j) acc += xt[j * 64 + lane] * we[j * 64 + lane];
#pragma unroll
    for (int off = 32; off; off >>= 1) acc += __shfl_xor(acc, off);
    lg[e] = acc;
  }
  if (lane == 0) {
    float m = lg[0];
#pragma unroll
    for (int e = 1; e < NEXP; ++e) m = fmaxf(m, lg[e]);
    float p[NEXP];
#pragma unroll
    for (int e = 0; e < NEXP; ++e) p[e] = __expf(lg[e] - m);
    int i0 = 0; float p0 = p[0];
#pragma unroll
    for (int e = 1; e < NEXP; ++e) if (p[e] > p0) { p0 = p[e]; i0 = e; }
    int i1 = -1; float p1 = -1.f;
#pragma unroll
    for (int e = 0; e < NEXP; ++e) if (e != i0 && p[e] > p1) { p1 = p[e]; i1 = e; }
    float wsum = p0 + p1;
#pragma unroll
    for (int e = 0; e < NEXP; ++e) logits[t * NEXP + e] = lg[e];
    topi[t * 2] = i0; topi[t * 2 + 1] = i1;
    topw[t * 2] = p0 / wsum; topw[t * 2 + 1] = p1 / wsum;
    atomicAdd(&counts[i0], 1); atomicAdd(&counts[i1], 1);
  }
}

__global__ void k_offsets(const int* __restrict__ counts, int* __restrict__ hbase) {
  if (threadIdx.x == 0) {
    int base = TD;  // shared-expert rows occupy h[0..2047]
    for (int e = 0; e < NEXP; ++e) { hbase[e] = base; base += (counts[e] + 127) & ~127; }
  }
}

__global__ void k_scatter(const int* __restrict__ topi, int* __restrict__ curs,
                          int* __restrict__ tokl, int* __restrict__ posarr) {
  int tid = blockIdx.x * 256 + threadIdx.x;
  if (tid >= TD * 2) return;
  int e = topi[tid];
  int pos = atomicAdd(&curs[e], 1);
  tokl[e * TD + pos] = tid >> 1;
  posarr[tid] = pos;
}

// ---------------- transpose + fp32->fp16 ----------------
__device__ __forceinline__ void transpose_tile(const float* __restrict__ src,
    _Float16* __restrict__ dst, int R, int C, int r0, int c0) {
  __shared__ _Float16 tile[64][68];
  int t = threadIdx.x;
#pragma unroll
  for (int i = 0; i < 4; ++i) {
    int r = (t >> 4) + i * 16;
    int c = (t & 15) * 4;
    float4 v = *(const float4*)(src + (size_t)(r0 + r) * C + c0 + c);
    *(f16x4*)&tile[r][c] = (f16x4){(_Float16)v.x, (_Float16)v.y, (_Float16)v.z, (_Float16)v.w};
  }
  __syncthreads();
#pragma unroll
  for (int i = 0; i < 2; ++i) {
    int cc = (t >> 3) + i * 32;
    int rr = (t & 7) * 8;
    f16x8 hv;
#pragma unroll
    for (int j = 0; j < 8; ++j) hv[j] = tile[rr + j][cc];
    *(f16x8*)(dst + (size_t)(c0 + cc) * R + r0 + rr) = hv;
  }
}

// phase 1: [1024][4096] mats: slot 0=sw1, 1=sw2, 2..9=w1[e], 10..17=w2[e]
__global__ __launch_bounds__(256) void k_tr1(const float* __restrict__ sw1, const float* __restrict__ sw2,
    const float* __restrict__ w1, const float* __restrict__ w2, _Float16* __restrict__ wt) {
  int id = blockIdx.y;
  const float* src = (id == 0) ? sw1 : (id == 1) ? sw2
                   : (id < 10) ? w1 + (size_t)(id - 2) * DD * HH
                               : w2 + (size_t)(id - 10) * DD * HH;
  _Float16* dst = wt + (size_t)id * WTSLOT;
  transpose_tile(src, dst, DD, HH, (blockIdx.x >> 6) * 64, (blockIdx.x & 63) * 64);
}

// phase 2 (after gemm1): [4096][1024] mats: 0=sw3, 1..8=w3[e]
__global__ __launch_bounds__(256) void k_tr2(const float* __restrict__ sw3,
    const float* __restrict__ w3, _Float16* __restrict__ wt) {
  int id = blockIdx.y;
  const float* src = (id == 0) ? sw3 : w3 + (size_t)(id - 1) * HH * DD;
  _Float16* dst = wt + (size_t)id * WTSLOT;
  transpose_tile(src, dst, HH, DD, (blockIdx.x >> 4) * 64, (blockIdx.x & 15) * 64);
}

// ---------------- GEMM1: h = silu(x@W1) * (x@W2), fp16 out ----------------
__global__ __launch_bounds__(256, 2) void k_gemm1(
    const _Float16* __restrict__ xh, const _Float16* __restrict__ wt,
    const int* __restrict__ counts, const int* __restrict__ hbase,
    const int* __restrict__ tok_list, _Float16* __restrict__ h) {
  __shared__ _Float16 lA[128 * 32];
  __shared__ _Float16 lB1[128 * 32];
  __shared__ _Float16 lB2[128 * 32];
  __shared__ int stok[128];

  int slot = blockIdx.y;
  const _Float16 *w1t, *w2t;
  int hrow0;
  if (slot < 16) {
    w1t = wt; w2t = wt + WTSLOT; hrow0 = slot * 128;
  } else {
    int e = (slot - 16) >> 4, rt = (slot - 16) & 15;
    if (rt * 128 >= counts[e]) return;
    w1t = wt + (size_t)(2 + e) * WTSLOT;
    w2t = wt + (size_t)(10 + e) * WTSLOT;
    hrow0 = hbase[e] + rt * 128;
  }
  if (threadIdx.x < 128) {
    int tok = (slot < 16) ? (hrow0 + threadIdx.x)
                          : tok_list[((slot - 16) >> 4) * TD + ((slot - 16) & 15) * 128 + threadIdx.x];
    stok[threadIdx.x] = tok;
  }
  __syncthreads();

  int n0 = blockIdx.x * 128;
  int wv = threadIdx.x >> 6, lane = threadIdx.x & 63;
  int wm = (wv & 1) * 64, wn = (wv >> 1) * 64;
  int qsel = lane >> 4;

  // per-lane staging sources: wave wv issues granule-rows j = 2wv, 2wv+1 of each tile
  const _Float16 *gA[2], *gB1[2], *gB2[2];
  int ldsoff[2];
#pragma unroll
  for (int jj = 0; jj < 2; ++jj) {
    int j = wv * 2 + jj;
    int n = j * 16 + (lane >> 2);
    int q = (lane & 3) ^ ((n >> 1) & 3);
    gA[jj]  = xh + (size_t)stok[n] * DD + q * 8;
    gB1[jj] = w1t + (size_t)(n0 + n) * DD + q * 8;
    gB2[jj] = w2t + (size_t)(n0 + n) * DD + q * 8;
    ldsoff[jj] = j * 1024 + lane * 16;
  }

  f32x4 acc1[4][4] = {}; f32x4 acc2[4][4] = {};

  for (int kk = 0; kk < DD; kk += 32) {
    __syncthreads();
#pragma unroll
    for (int jj = 0; jj < 2; ++jj) {
      gld16((char*)lA + ldsoff[jj], gA[jj] + kk);
      gld16((char*)lB1 + ldsoff[jj], gB1[jj] + kk);
      gld16((char*)lB2 + ldsoff[jj], gB2[jj] + kk);
    }
    __syncthreads();
    f16x8 af[4];
#pragma unroll
    for (int mi = 0; mi < 4; ++mi) af[mi] = frag_ld(lA, wm + mi * 16 + (lane & 15), qsel);
#pragma unroll
    for (int ni = 0; ni < 4; ++ni) {
      f16x8 b1 = frag_ld(lB1, wn + ni * 16 + (lane & 15), qsel);
      f16x8 b2 = frag_ld(lB2, wn + ni * 16 + (lane & 15), qsel);
#pragma unroll
      for (int mi = 0; mi < 4; ++mi) {
        acc1[mi][ni] = __builtin_amdgcn_mfma_f32_16x16x32_f16(af[mi], b1, acc1[mi][ni], 0, 0, 0);
        acc2[mi][ni] = __builtin_amdgcn_mfma_f32_16x16x32_f16(af[mi], b2, acc2[mi][ni], 0, 0, 0);
      }
    }
  }
#pragma unroll
  for (int mi = 0; mi < 4; ++mi)
#pragma unroll
    for (int ni = 0; ni < 4; ++ni)
#pragma unroll
      for (int i = 0; i < 4; ++i) {
        int r = wm + mi * 16 + (lane >> 4) * 4 + i;
        int c = wn + ni * 16 + (lane & 15);
        float a = acc1[mi][ni][i], b = acc2[mi][ni][i];
        h[(size_t)(hrow0 + r) * HH + n0 + c] = (_Float16)((a / (1.f + __expf(-a))) * b);
      }
}

// ---------------- GEMM2: y_z = h @ W3 (split-K partials, fp16, no atomics) ----------------
__global__ __launch_bounds__(256, 2) void k_gemm2(
    const _Float16* __restrict__ h, const _Float16* __restrict__ wt,
    const int* __restrict__ counts, const int* __restrict__ hbase,
    _Float16* __restrict__ y0, _Float16* __restrict__ y1) {
  __shared__ _Float16 lA[128 * 32];
  __shared__ _Float16 lB[128 * 32];

  int slot = blockIdx.y;
  const _Float16* w3t;
  int hrow0;
  if (slot < 16) {
    w3t = wt; hrow0 = slot * 128;
  } else {
    int e = (slot - 16) >> 4, rt = (slot - 16) & 15;
    if (rt * 128 >= counts[e]) return;
    w3t = wt + (size_t)(1 + e) * WTSLOT;
    hrow0 = hbase[e] + rt * 128;
  }
  _Float16* y = blockIdx.z ? y1 : y0;
  int kz0 = blockIdx.z * (HH / 2);

  int n0 = blockIdx.x * 128;
  int wv = threadIdx.x >> 6, lane = threadIdx.x & 63;
  int wm = (wv & 1) * 64, wn = (wv >> 1) * 64;
  int qsel = lane >> 4;

  const _Float16 *gA[2], *gB[2];
  int ldsoff[2];
#pragma unroll
  for (int jj = 0; jj < 2; ++jj) {
    int j = wv * 2 + jj;
    int n = j * 16 + (lane >> 2);
    int q = (lane & 3) ^ ((n >> 1) & 3);
    gA[jj] = h   + (size_t)(hrow0 + n) * HH + kz0 + q * 8;
    gB[jj] = w3t + (size_t)(n0 + n)   * HH + kz0 + q * 8;
    ldsoff[jj] = j * 1024 + lane * 16;
  }

  f32x4 acc[4][4] = {};
  for (int kk = 0; kk < HH / 2; kk += 32) {
    __syncthreads();
#pragma unroll
    for (int jj = 0; jj < 2; ++jj) {
      gld16((char*)lA + ldsoff[jj], gA[jj] + kk);
      gld16((char*)lB + ldsoff[jj], gB[jj] + kk);
    }
    __syncthreads();
    f16x8 af[4];
#pragma unroll
    for (int mi = 0; mi < 4; ++mi) af[mi] = frag_ld(lA, wm + mi * 16 + (lane & 15), qsel);
#pragma unroll
    for (int ni = 0; ni < 4; ++ni) {
      f16x8 bf = frag_ld(lB, wn + ni * 16 + (lane & 15), qsel);
#pragma unroll
      for (int mi = 0; mi < 4; ++mi)
        acc[mi][ni] = __builtin_amdgcn_mfma_f32_16x16x32_f16(af[mi], bf, acc[mi][ni], 0, 0, 0);
    }
  }
#pragma unroll
  for (int mi = 0; mi < 4; ++mi)
#pragma unroll
    for (int ni = 0; ni < 4; ++ni)
#pragma unroll
      for (int i = 0; i < 4; ++i) {
        int r = wm + mi * 16 + (lane >> 4) * 4 + i;
        int c = wn + ni * 16 + (lane & 15);
        y[(size_t)(hrow0 + r) * DD + n0 + c] = (_Float16)acc[mi][ni][i];
      }
}

// ---------------- combine: out[t] = y_sh[t] + w0*y[r0] + w1*y[r1] ----------------
__global__ __launch_bounds__(256) void k_combine(
    const _Float16* __restrict__ y0, const _Float16* __restrict__ y1,
    const int* __restrict__ topi, const float* __restrict__ topw,
    const int* __restrict__ posarr, const int* __restrict__ hbase,
    float* __restrict__ out) {
  int t = blockIdx.x;
  int c = threadIdx.x * 4;
  int e0 = topi[2 * t], e1 = topi[2 * t + 1];
  float w0 = topw[2 * t], w1 = topw[2 * t + 1];
  size_t rs = (size_t)t * DD + c;
  size_t r0 = (size_t)(hbase[e0] + posarr[2 * t]) * DD + c;
  size_t r1 = (size_t)(hbase[e1] + posarr[2 * t + 1]) * DD + c;
  f16x4 s0 = *(const f16x4*)(y0 + rs), s1 = *(const f16x4*)(y1 + rs);
  f16x4 a0 = *(const f16x4*)(y0 + r0), a1 = *(const f16x4*)(y1 + r0);
  f16x4 b0 = *(const f16x4*)(y0 + r1), b1 = *(const f16x4*)(y1 + r1);
  float4 o;
  float* op = &o.x;
#pragma unroll
  for (int i = 0; i < 4; ++i)
    op[i] = (float)s0[i] + (float)s1[i] + w0 * ((float)a0[i] + (float)a1[i])
          + w1 * ((float)b0[i] + (float)b1[i]);
  *(float4*)(out + rs) = o;
}

// ---------------- launcher ----------------
extern "C" void kernel_launch(void* const* d_in, const int* in_sizes, int n_in,
                              void* d_out, int out_size, void* d_ws, size_t ws_size,
                              hipStream_t stream) {
  const float* x   = (const float*)d_in[0];
  const float* sw1 = (const float*)d_in[1];
  const float* sw2 = (const float*)d_in[2];
  const float* sw3 = (const float*)d_in[3];
  const float* w1  = (const float*)d_in[4];
  const float* w2  = (const float*)d_in[5];
  const float* w3  = (const float*)d_in[6];
  const float* rw  = (const float*)d_in[7];
  float* out = (float*)d_out;
  char* ws = (char*)d_ws;

  int*   counts = (int*)(ws + WS_COUNTS);
  int*   curs   = (int*)(ws + WS_CURS);
  int*   hbase  = (int*)(ws + WS_HBASE);
  int*   tokl   = (int*)(ws + WS_TOKLIST);
  int*   topi   = (int*)(ws + WS_TOPI);
  float* topw   = (float*)(ws + WS_TOPW);
  int*   posarr = (int*)(ws + WS_POS);
  _Float16* xh   = (_Float16*)(ws + WS_XH);
  _Float16* hbuf = (_Float16*)(ws + WS_H);
  _Float16* wt   = (_Float16*)(ws + WS_WT);
  _Float16* ybuf0 = wt + 9 * WTSLOT;   // dead w1t-expert slots during gemm2
  _Float16* ybuf1 = wt + 11 * WTSLOT;

  hipMemsetAsync(ws, 0, 65792, stream);  // counts/curs + tok lists (pad-token safety)

  k_xh<<<TD * DD / 2048, 256, 0, stream>>>(x, xh);
  k_router<<<TD / 4, 256, 0, stream>>>(x, rw, out + (size_t)TD * DD, topi, topw, counts);
  k_offsets<<<1, 64, 0, stream>>>(counts, hbase);
  k_scatter<<<16, 256, 0, stream>>>(topi, curs, tokl, posarr);

  k_tr1<<<dim3(1024, 18), 256, 0, stream>>>(sw1, sw2, w1, w2, wt);
  k_gemm1<<<dim3(HH / 128, 144), 256, 0, stream>>>(xh, wt, counts, hbase, tokl, hbuf);
  k_tr2<<<dim3(1024, 9), 256, 0, stream>>>(sw3, w3, wt);
  k_gemm2<<<dim3(DD / 128, 144, 2), 256, 0, stream>>>(hbuf, wt, counts, hbase, ybuf0, ybuf1);
  k_combine<<<TD, 256, 0, stream>>>(ybuf0, ybuf1, topi, topw, posarr, hbase, out);
}